// Round 1
// baseline (1064.782 us; speedup 1.0000x reference)
//
#include <hip/hip_runtime.h>
#include <hip/hip_bf16.h>

// Problem constants (from reference)
constexpr int Bc = 4, Tc = 24, Nn = 4096, Fc = 128;
constexpr int Rr = 32, Hh = 4, Dd = 32;
constexpr int BT = Bc * Tc;                 // 96
constexpr float SCALE = 0.17677669529663687f; // 1/sqrt(32)

// Workspace layout (floats):
//   expa : [BT][Nn][Hh*Rr]          50331648
//   v1   : [BT][Hh][Rr][Dd]           393216   (atomically accumulated -> zeroed)
//   Z    : [BT][Hh][Rr]                12288   (atomically accumulated -> zeroed)
//   v1z  : [BT][Hh][Dd][Rr]           393216
constexpr size_t OFF_EXPA = 0;
constexpr size_t OFF_V1   = (size_t)BT * Nn * Hh * Rr;          // 50331648
constexpr size_t OFF_Z    = OFF_V1 + (size_t)BT * Hh * Rr * Dd; // 50724864
constexpr size_t OFF_V1Z  = OFF_Z + (size_t)BT * Hh * Rr;       // 50737152

// ---------------------------------------------------------------------------
// k1a: q = x @ Wq^T + bq  ->  attn -> expa (and that's it; sums come later)
// Block: 256 threads, 64 nodes of one bt. LDS: XT[k][n] (also reused as QS),
// WT[k][j-half]. Two j-halves staged sequentially so LDS stays at ~70 KB
// (2 blocks/CU).
// ---------------------------------------------------------------------------
__global__ __launch_bounds__(256, 2)
void k1a(const float* __restrict__ x, const float* __restrict__ Wq,
         const float* __restrict__ bq, const float* __restrict__ key,
         float* __restrict__ expa)
{
    __shared__ float XT[128 * 68];   // [k][n] padded 68; reused as QS[64][136]
    __shared__ float WT[128 * 68];   // [k][jloc] padded 68

    const int t  = threadIdx.x;
    const int bt = blockIdx.y;
    const int n0 = blockIdx.x * 64;

    // ---- stage XT (transposed x tile). thread t owns row n=t&63, quarter kq.
    {
        const float4* xb4 = (const float4*)(x + ((size_t)bt * Nn + n0) * Fc);
        const int n  = t & 63;
        const int kq = t >> 6;
#pragma unroll
        for (int i = 0; i < 8; i++) {
            const int k4 = i * 4 + kq;
            float4 v = xb4[(size_t)n * 32 + k4];
            XT[(k4 * 4 + 0) * 68 + n] = v.x;
            XT[(k4 * 4 + 1) * 68 + n] = v.y;
            XT[(k4 * 4 + 2) * 68 + n] = v.z;
            XT[(k4 * 4 + 3) * 68 + n] = v.w;
        }
    }

    const int jg = t & 15;   // 16 j-groups of 4 (within 64-wide j-half)
    const int ng = t >> 4;   // 16 node-groups of 4

    float acc[2][4][4];
#pragma unroll
    for (int h2 = 0; h2 < 2; h2++)
#pragma unroll
        for (int a = 0; a < 4; a++)
#pragma unroll
            for (int b = 0; b < 4; b++) acc[h2][a][b] = 0.f;

#pragma unroll
    for (int half = 0; half < 2; half++) {
        // stage WT for this j-half (transposed)
        {
            const float4* wb4 = (const float4*)(Wq + (size_t)half * 64 * Fc);
            const int j  = t & 63;
            const int kq = t >> 6;
#pragma unroll
            for (int i = 0; i < 8; i++) {
                const int k4 = i * 4 + kq;
                float4 v = wb4[(size_t)j * 32 + k4];
                WT[(k4 * 4 + 0) * 68 + j] = v.x;
                WT[(k4 * 4 + 1) * 68 + j] = v.y;
                WT[(k4 * 4 + 2) * 68 + j] = v.z;
                WT[(k4 * 4 + 3) * 68 + j] = v.w;
            }
        }
        __syncthreads();

#pragma unroll 8
        for (int k = 0; k < 128; k++) {
            float4 xa = *(const float4*)&XT[k * 68 + ng * 4];
            float4 wa = *(const float4*)&WT[k * 68 + jg * 4];
            acc[half][0][0] += xa.x * wa.x; acc[half][0][1] += xa.x * wa.y;
            acc[half][0][2] += xa.x * wa.z; acc[half][0][3] += xa.x * wa.w;
            acc[half][1][0] += xa.y * wa.x; acc[half][1][1] += xa.y * wa.y;
            acc[half][1][2] += xa.y * wa.z; acc[half][1][3] += xa.y * wa.w;
            acc[half][2][0] += xa.z * wa.x; acc[half][2][1] += xa.z * wa.y;
            acc[half][2][2] += xa.z * wa.z; acc[half][2][3] += xa.z * wa.w;
            acc[half][3][0] += xa.w * wa.x; acc[half][3][1] += xa.w * wa.y;
            acc[half][3][2] += xa.w * wa.z; acc[half][3][3] += xa.w * wa.w;
        }
        __syncthreads();   // reads done before restage / before QS overwrite
    }

    // ---- write q tile into QS (reuse XT buffer), add bias
    float* QS = XT;   // [64][136]
#pragma unroll
    for (int half = 0; half < 2; half++)
#pragma unroll
        for (int nn = 0; nn < 4; nn++)
#pragma unroll
            for (int jj = 0; jj < 4; jj++) {
                const int j = half * 64 + jg * 4 + jj;
                QS[(ng * 4 + nn) * 136 + j] = acc[half][nn][jj] + bq[j];
            }
    __syncthreads();

    // ---- attn + exp. thread = (h,r) pair x 32 nodes; key row in registers.
    {
        const int hr = t & 127, nh = t >> 7;
        const int h = hr >> 5, r = hr & 31;
        float4 kreg[8];
        const float4* kp = (const float4*)(key + ((size_t)r * Hh + h) * Dd);
#pragma unroll
        for (int d4 = 0; d4 < 8; d4++) kreg[d4] = kp[d4];

        float* eout = expa + ((size_t)bt * Nn + n0) * (Hh * Rr);
#pragma unroll 4
        for (int i = 0; i < 32; i++) {
            const int n = nh * 32 + i;
            const float4* qrow = (const float4*)&QS[n * 136 + h * 32];
            float a = 0.f;
#pragma unroll
            for (int d4 = 0; d4 < 8; d4++) {
                float4 qv = qrow[d4];
                a += qv.x * kreg[d4].x + qv.y * kreg[d4].y +
                     qv.z * kreg[d4].z + qv.w * kreg[d4].w;
            }
            eout[(size_t)n * 128 + hr] = __expf(a * SCALE);
        }
    }
}

// ---------------------------------------------------------------------------
// k1b: xv = x @ Wv^T + bv  -> d_out (xv lives in d_out until k3 overwrites it)
// ---------------------------------------------------------------------------
__global__ __launch_bounds__(256, 2)
void k1b(const float* __restrict__ x, const float* __restrict__ Wv,
         const float* __restrict__ bv, float* __restrict__ out)
{
    __shared__ float XT[128 * 68];
    __shared__ float WT[128 * 68];

    const int t  = threadIdx.x;
    const int bt = blockIdx.y;
    const int n0 = blockIdx.x * 64;

    {
        const float4* xb4 = (const float4*)(x + ((size_t)bt * Nn + n0) * Fc);
        const int n  = t & 63;
        const int kq = t >> 6;
#pragma unroll
        for (int i = 0; i < 8; i++) {
            const int k4 = i * 4 + kq;
            float4 v = xb4[(size_t)n * 32 + k4];
            XT[(k4 * 4 + 0) * 68 + n] = v.x;
            XT[(k4 * 4 + 1) * 68 + n] = v.y;
            XT[(k4 * 4 + 2) * 68 + n] = v.z;
            XT[(k4 * 4 + 3) * 68 + n] = v.w;
        }
    }

    const int jg = t & 15;
    const int ng = t >> 4;

    float acc[2][4][4];
#pragma unroll
    for (int h2 = 0; h2 < 2; h2++)
#pragma unroll
        for (int a = 0; a < 4; a++)
#pragma unroll
            for (int b = 0; b < 4; b++) acc[h2][a][b] = 0.f;

#pragma unroll
    for (int half = 0; half < 2; half++) {
        {
            const float4* wb4 = (const float4*)(Wv + (size_t)half * 64 * Fc);
            const int j  = t & 63;
            const int kq = t >> 6;
#pragma unroll
            for (int i = 0; i < 8; i++) {
                const int k4 = i * 4 + kq;
                float4 v = wb4[(size_t)j * 32 + k4];
                WT[(k4 * 4 + 0) * 68 + j] = v.x;
                WT[(k4 * 4 + 1) * 68 + j] = v.y;
                WT[(k4 * 4 + 2) * 68 + j] = v.z;
                WT[(k4 * 4 + 3) * 68 + j] = v.w;
            }
        }
        __syncthreads();

#pragma unroll 8
        for (int k = 0; k < 128; k++) {
            float4 xa = *(const float4*)&XT[k * 68 + ng * 4];
            float4 wa = *(const float4*)&WT[k * 68 + jg * 4];
            acc[half][0][0] += xa.x * wa.x; acc[half][0][1] += xa.x * wa.y;
            acc[half][0][2] += xa.x * wa.z; acc[half][0][3] += xa.x * wa.w;
            acc[half][1][0] += xa.y * wa.x; acc[half][1][1] += xa.y * wa.y;
            acc[half][1][2] += xa.y * wa.z; acc[half][1][3] += xa.y * wa.w;
            acc[half][2][0] += xa.z * wa.x; acc[half][2][1] += xa.z * wa.y;
            acc[half][2][2] += xa.z * wa.z; acc[half][2][3] += xa.z * wa.w;
            acc[half][3][0] += xa.w * wa.x; acc[half][3][1] += xa.w * wa.y;
            acc[half][3][2] += xa.w * wa.z; acc[half][3][3] += xa.w * wa.w;
        }
        __syncthreads();
    }

    // store xv tile (with bias) to d_out
    float* op = out + ((size_t)bt * Nn + n0) * Fc;
#pragma unroll
    for (int half = 0; half < 2; half++)
#pragma unroll
        for (int nn = 0; nn < 4; nn++) {
            const int j = half * 64 + jg * 4;
            float4 v;
            v.x = acc[half][nn][0] + bv[j + 0];
            v.y = acc[half][nn][1] + bv[j + 1];
            v.z = acc[half][nn][2] + bv[j + 2];
            v.w = acc[half][nn][3] + bv[j + 3];
            *(float4*)&op[(size_t)(ng * 4 + nn) * 128 + j] = v;
        }
}

// ---------------------------------------------------------------------------
// k2: per (bt, h, n-segment): v1[r][d] += sum_n s1[n][r]*xv[n][d],
//     Z[r] += sum_n expa[n][r].  s1 row-normalization computed in-kernel.
// ---------------------------------------------------------------------------
__global__ __launch_bounds__(256, 4)
void k2(const float* __restrict__ expa, const float* __restrict__ xv,
        float* __restrict__ v1, float* __restrict__ Z)
{
    __shared__ float ea[64 * 32];    // expa chunk [n][r]
    __shared__ float xvs[64 * 40];   // xv chunk [n][d] padded 40 (16B rows)
    __shared__ float srw[64];        // 1/sum_r expa per node

    const int t  = threadIdx.x;
    const int bt = blockIdx.z;
    const int h  = blockIdx.y;
    const int nbase = blockIdx.x * 1024;

    const int r  = t >> 3;   // 0..31
    const int dg = t & 7;    // d-group of 4

    float a0 = 0.f, a1 = 0.f, a2 = 0.f, a3 = 0.f, zacc = 0.f;

    for (int chunk = 0; chunk < 16; chunk++) {
        const int nc = nbase + chunk * 64;
        // stage
#pragma unroll
        for (int i = 0; i < 2; i++) {
            const int n  = i * 32 + (t >> 3);
            const int r4 = t & 7;
            const size_t gn = (size_t)bt * Nn + nc + n;
            ((float4*)&ea[n * 32])[r4] =
                ((const float4*)(expa + gn * 128 + h * 32))[r4];
            ((float4*)&xvs[n * 40])[r4] =
                ((const float4*)(xv + gn * 128 + h * 32))[r4];
        }
        __syncthreads();
        if (t < 64) {
            float s = 0.f;
#pragma unroll
            for (int rp = 0; rp < 32; rp++) s += ea[t * 32 + ((rp + t) & 31)];
            srw[t] = 1.f / s;
        }
        __syncthreads();
#pragma unroll 4
        for (int n = 0; n < 64; n++) {
            const float e = ea[n * 32 + r];
            const float s = e * srw[n];
            float4 xq = *(const float4*)&xvs[n * 40 + dg * 4];
            a0 += s * xq.x; a1 += s * xq.y; a2 += s * xq.z; a3 += s * xq.w;
            zacc += e;
        }
        __syncthreads();
    }

    float* v1p = v1 + (((size_t)bt * Hh + h) * Rr + r) * Dd + dg * 4;
    atomicAdd(v1p + 0, a0);
    atomicAdd(v1p + 1, a1);
    atomicAdd(v1p + 2, a2);
    atomicAdd(v1p + 3, a3);
    if (dg == 0) atomicAdd(Z + ((size_t)bt * Hh + h) * Rr + r, zacc);
}

// ---------------------------------------------------------------------------
// k2b: v1z[bt][h][d][r] = v1[bt][h][r][d] / Z[bt][h][r]   (transpose + scale)
// ---------------------------------------------------------------------------
__global__ void k2b(const float* __restrict__ v1, const float* __restrict__ Z,
                    float* __restrict__ v1z)
{
    const int idx = blockIdx.x * 256 + threadIdx.x;   // interpreted as [bt][h][d][r]
    const int r = idx & 31, d = (idx >> 5) & 31, h = (idx >> 10) & 3, bt = idx >> 12;
    const float z = Z[((size_t)bt * Hh + h) * Rr + r];
    v1z[idx] = v1[(((size_t)bt * Hh + h) * Rr + r) * Dd + d] / z;
}

// ---------------------------------------------------------------------------
// k3: v2[n,h,d] = sum_r expa[n,h,r] * v1z[h][d][r];
//     out = sigmoid(alpha_h)*xv + sigmoid(beta_h)*v2   (in place over d_out)
// ---------------------------------------------------------------------------
__global__ __launch_bounds__(256, 2)
void k3(const float* __restrict__ expa, const float* __restrict__ v1z,
        const float* __restrict__ alpha, const float* __restrict__ beta,
        float* __restrict__ out)
{
    __shared__ float eas[32 * 132];   // expa tile [n][hr], rows 528B (16B aligned)

    const int t  = threadIdx.x;
    const int bt = blockIdx.y;
    const int n0 = blockIdx.x * 32;

    // stage expa tile (coalesced)
#pragma unroll
    for (int i = 0; i < 4; i++) {
        const int idx = i * 256 + t;
        const int n = idx >> 5, c4 = idx & 31;
        ((float4*)&eas[n * 132])[c4] =
            ((const float4*)(expa + ((size_t)bt * Nn + n0 + n) * 128))[c4];
    }

    const int j = t & 127, nh = t >> 7;
    const int h = j >> 5, d = j & 31;

    // v1z row for this (h,d) in registers (hot in L2/L3: 16 KB per bt)
    float4 vz[8];
    const float4* vp =
        (const float4*)(v1z + (((size_t)bt * Hh + h) * Dd + d) * Rr);
#pragma unroll
    for (int i = 0; i < 8; i++) vz[i] = vp[i];

    const float sa = 1.f / (1.f + __expf(-alpha[h]));
    const float sb = 1.f / (1.f + __expf(-beta[h]));

    __syncthreads();

    float* op = out + ((size_t)bt * Nn + n0) * Fc;
#pragma unroll 2
    for (int i = 0; i < 16; i++) {
        const int n = nh * 16 + i;
        const float4* er = (const float4*)&eas[n * 132 + h * 32];
        float v2 = 0.f;
#pragma unroll
        for (int r4 = 0; r4 < 8; r4++) {
            float4 e4 = er[r4];
            v2 += e4.x * vz[r4].x + e4.y * vz[r4].y +
                  e4.z * vz[r4].z + e4.w * vz[r4].w;
        }
        const size_t oi = (size_t)n * 128 + j;
        const float xvv = op[oi];
        op[oi] = sa * xvv + sb * v2;
    }
}

// ---------------------------------------------------------------------------
extern "C" void kernel_launch(void* const* d_in, const int* in_sizes, int n_in,
                              void* d_out, int out_size, void* d_ws, size_t ws_size,
                              hipStream_t stream)
{
    const float* x     = (const float*)d_in[0];
    const float* Wq    = (const float*)d_in[1];
    const float* bq    = (const float*)d_in[2];
    const float* key   = (const float*)d_in[3];
    const float* Wv    = (const float*)d_in[4];
    const float* bv    = (const float*)d_in[5];
    const float* alpha = (const float*)d_in[6];
    const float* beta  = (const float*)d_in[7];
    float* out = (float*)d_out;

    float* ws   = (float*)d_ws;
    float* expa = ws + OFF_EXPA;
    float* v1   = ws + OFF_V1;
    float* Z    = ws + OFF_Z;
    float* v1z  = ws + OFF_V1Z;

    // zero the atomically-accumulated buffers (v1 and Z are contiguous)
    hipMemsetAsync(v1, 0, (size_t)(BT * Hh * Rr * Dd + BT * Hh * Rr) * sizeof(float),
                   stream);

    k1a<<<dim3(Nn / 64, BT), 256, 0, stream>>>(x, Wq, bq, key, expa);
    k1b<<<dim3(Nn / 64, BT), 256, 0, stream>>>(x, Wv, bv, out);
    k2<<<dim3(4, Hh, BT), 256, 0, stream>>>(expa, out, v1, Z);
    k2b<<<dim3(BT * Hh * Rr * Dd / 256), 256, 0, stream>>>(v1, Z, v1z);
    k3<<<dim3(Nn / 32, BT), 256, 0, stream>>>(expa, v1z, alpha, beta, out);
}

// Round 2
// 786.211 us; speedup vs baseline: 1.3543x; 1.3543x over previous
//
#include <hip/hip_runtime.h>
#include <hip/hip_bf16.h>

// Problem constants (from reference)
constexpr int Bc = 4, Tc = 24, Nn = 4096, Fc = 128;
constexpr int Rr = 32, Hh = 4, Dd = 32;
constexpr int BT = Bc * Tc;                 // 96
constexpr float SCALE = 0.17677669529663687f; // 1/sqrt(32)

// Workspace layout (floats):
//   expa : [BT][Nn][Hh*Rr]          50331648
//   v1   : [BT][Hh][Rr][Dd]           393216   (atomically accumulated -> zeroed)
//   Z    : [BT][Hh][Rr]                12288   (atomically accumulated -> zeroed)
//   v1z  : [BT][Hh][Dd][Rr]           393216   (ALSO aliased early as bf16 W/key
//                                               buffers: dead by the time k2b writes)
constexpr size_t OFF_EXPA = 0;
constexpr size_t OFF_V1   = (size_t)BT * Nn * Hh * Rr;          // 50331648
constexpr size_t OFF_Z    = OFF_V1 + (size_t)BT * Hh * Rr * Dd; // 50724864
constexpr size_t OFF_V1Z  = OFF_Z + (size_t)BT * Hh * Rr;       // 50737152

// bf16 param buffer (ushort), aliasing v1z region (147 KB < 1.5 MB):
//   Wqhi[128*128], Wqlo, Wvhi, Wvlo, Khi[32*4*32], Klo
constexpr int U_WQHI = 0, U_WQLO = 16384, U_WVHI = 32768, U_WVLO = 49152;
constexpr int U_KHI = 65536, U_KLO = 69632, U_TOTAL = 73728;

using short8  = __attribute__((ext_vector_type(8))) short;
using floatx4 = __attribute__((ext_vector_type(4))) float;

__device__ inline ushort f2bf(float f) {
    union { float f; unsigned u; } c{f};
    unsigned r = c.u + 0x7fffu + ((c.u >> 16) & 1u);  // RNE
    return (ushort)(r >> 16);
}
__device__ inline float bf2f(ushort u) {
    union { unsigned u; float f; } c{(unsigned)u << 16};
    return c.f;
}

// ---------------------------------------------------------------------------
// kprep: split Wq, Wv, key_param into bf16 hi/lo pairs (tiny, L2-resident)
// ---------------------------------------------------------------------------
__global__ void kprep(const float* __restrict__ Wq, const float* __restrict__ Wv,
                      const float* __restrict__ key, ushort* __restrict__ U)
{
    const int idx = blockIdx.x * 256 + threadIdx.x;   // 0..36863
    float v; int hi_off, lo_off, off;
    if (idx < 16384)      { v = Wq[idx];          hi_off = U_WQHI; lo_off = U_WQLO; off = idx; }
    else if (idx < 32768) { v = Wv[idx - 16384];  hi_off = U_WVHI; lo_off = U_WVLO; off = idx - 16384; }
    else                  { v = key[idx - 32768]; hi_off = U_KHI;  lo_off = U_KLO;  off = idx - 32768; }
    ushort h = f2bf(v);
    U[hi_off + off] = h;
    U[lo_off + off] = f2bf(v - bf2f(h));
}

// ---------------------------------------------------------------------------
// k1 (fused): per 64-node tile:
//   q  = x@Wq^T + bq   (3-term bf16 MFMA)    -> per-wave LDS roundtrip ->
//   attn = q.key/sqrt(D), expa = exp(attn)   (3-term bf16 MFMA)        -> expa
//   xv = x@Wv^T + bv   (3-term bf16 MFMA)                              -> d_out
// Wave w owns head w: q-cols [32w,32w+32), v-cols [32w,32w+32), attn head w.
// x staged once as hi/lo bf16 in LDS; W/key frags stream from global (L2-hot).
// Only ONE __syncthreads (after x staging); everything else is wave-local
// (DS ops are in-order per wave).
// ---------------------------------------------------------------------------
__global__ __launch_bounds__(256, 2)
void k1(const float* __restrict__ x, const float* __restrict__ bq,
        const float* __restrict__ bv, const ushort* __restrict__ U,
        float* __restrict__ expa, float* __restrict__ out)
{
    // xhi [64][136]bf16 17408 B | xlo 17408 B | 4x per-wave scratch 10240 B
    __shared__ __align__(16) char lds[75776];
    ushort* xhi = (ushort*)lds;
    ushort* xlo = (ushort*)(lds + 17408);

    const int t    = threadIdx.x;
    const int w    = t >> 6;          // wave = head
    const int lane = t & 63;
    const int quad = lane >> 4, l15 = lane & 15;
    const int bt   = blockIdx.y;
    const int n0   = blockIdx.x * 64;

    char*   wsc  = lds + 34816 + w * 10240;   // per-wave scratch
    ushort* qhiS = (ushort*)wsc;              // [64][40] bf16
    ushort* qloS = (ushort*)(wsc + 5120);     // [64][40] bf16
    float*  fS   = (float*)wsc;               // overlay [64][32] f32

    // ---- stage x tile -> hi/lo bf16 LDS (coalesced float4 reads)
    const float4* xg = (const float4*)(x + ((size_t)bt * Nn + n0) * Fc);
#pragma unroll
    for (int i = 0; i < 8; i++) {
        const int idx = i * 256 + t;
        const int row = idx >> 5, c4 = idx & 31;
        float4 v = xg[idx];
        ushort h0 = f2bf(v.x), h1 = f2bf(v.y), h2 = f2bf(v.z), h3 = f2bf(v.w);
        ushort4 hv; hv.x = h0; hv.y = h1; hv.z = h2; hv.w = h3;
        ushort4 lv; lv.x = f2bf(v.x - bf2f(h0)); lv.y = f2bf(v.y - bf2f(h1));
        lv.z = f2bf(v.z - bf2f(h2)); lv.w = f2bf(v.w - bf2f(h3));
        *(ushort4*)&xhi[row * 136 + c4 * 4] = hv;
        *(ushort4*)&xlo[row * 136 + c4 * 4] = lv;
    }
    __syncthreads();

    const ushort* Wqhi = U + U_WQHI; const ushort* Wqlo = U + U_WQLO;
    const ushort* Wvhi = U + U_WVHI; const ushort* Wvlo = U + U_WVLO;
    const ushort* Khi  = U + U_KHI;  const ushort* Klo  = U + U_KLO;

    floatx4 accq[4][2], accv[4][2];
#pragma unroll
    for (int mt = 0; mt < 4; mt++)
#pragma unroll
        for (int nt = 0; nt < 2; nt++) {
            accq[mt][nt] = (floatx4)0.f;
            accv[mt][nt] = (floatx4)0.f;
        }

    // ---- K-loop: 4 chunks of K=32
#pragma unroll
    for (int kc = 0; kc < 4; kc++) {
        short8 ahi[4], alo[4];
#pragma unroll
        for (int mt = 0; mt < 4; mt++) {
            const int ro = (16 * mt + l15) * 136 + kc * 32 + quad * 8;
            ahi[mt] = *(const short8*)&xhi[ro];
            alo[mt] = *(const short8*)&xlo[ro];
        }
        short8 qbh[2], qbl[2], vbh[2], vbl[2];
#pragma unroll
        for (int nt = 0; nt < 2; nt++) {
            const int off = (32 * w + 16 * nt + l15) * 128 + kc * 32 + quad * 8;
            qbh[nt] = *(const short8*)&Wqhi[off];
            qbl[nt] = *(const short8*)&Wqlo[off];
            vbh[nt] = *(const short8*)&Wvhi[off];
            vbl[nt] = *(const short8*)&Wvlo[off];
        }
#pragma unroll
        for (int mt = 0; mt < 4; mt++)
#pragma unroll
            for (int nt = 0; nt < 2; nt++) {
                accq[mt][nt] = __builtin_amdgcn_mfma_f32_16x16x32_bf16(ahi[mt], qbh[nt], accq[mt][nt], 0, 0, 0);
                accq[mt][nt] = __builtin_amdgcn_mfma_f32_16x16x32_bf16(ahi[mt], qbl[nt], accq[mt][nt], 0, 0, 0);
                accq[mt][nt] = __builtin_amdgcn_mfma_f32_16x16x32_bf16(alo[mt], qbh[nt], accq[mt][nt], 0, 0, 0);
                accv[mt][nt] = __builtin_amdgcn_mfma_f32_16x16x32_bf16(ahi[mt], vbh[nt], accv[mt][nt], 0, 0, 0);
                accv[mt][nt] = __builtin_amdgcn_mfma_f32_16x16x32_bf16(ahi[mt], vbl[nt], accv[mt][nt], 0, 0, 0);
                accv[mt][nt] = __builtin_amdgcn_mfma_f32_16x16x32_bf16(alo[mt], vbh[nt], accv[mt][nt], 0, 0, 0);
            }
    }

    // ---- q epilogue: +bq, hi/lo split into per-wave LDS (C-layout -> A-layout)
    float bqv[2], bvv[2];
#pragma unroll
    for (int nt = 0; nt < 2; nt++) {
        bqv[nt] = bq[32 * w + 16 * nt + l15];
        bvv[nt] = bv[32 * w + 16 * nt + l15];
    }
#pragma unroll
    for (int mt = 0; mt < 4; mt++)
#pragma unroll
        for (int nt = 0; nt < 2; nt++)
#pragma unroll
            for (int reg = 0; reg < 4; reg++) {
                const int row = 16 * mt + quad * 4 + reg;
                const int col = 16 * nt + l15;
                const float qv = accq[mt][nt][reg] + bqv[nt];
                const ushort h = f2bf(qv);
                qhiS[row * 40 + col] = h;
                qloS[row * 40 + col] = f2bf(qv - bf2f(h));
            }

    // ---- attn MFMA: A = q (A-layout from LDS), B = key head w
    short8 qah[4], qal[4], kbh[2], kbl[2];
#pragma unroll
    for (int mt = 0; mt < 4; mt++) {
        const int ro = (16 * mt + l15) * 40 + quad * 8;
        qah[mt] = *(const short8*)&qhiS[ro];
        qal[mt] = *(const short8*)&qloS[ro];
    }
#pragma unroll
    for (int rt = 0; rt < 2; rt++) {
        const int off = ((16 * rt + l15) * 4 + w) * 32 + quad * 8;
        kbh[rt] = *(const short8*)&Khi[off];
        kbl[rt] = *(const short8*)&Klo[off];
    }
    floatx4 acca[4][2];
#pragma unroll
    for (int mt = 0; mt < 4; mt++)
#pragma unroll
        for (int rt = 0; rt < 2; rt++) {
            acca[mt][rt] = (floatx4)0.f;
            acca[mt][rt] = __builtin_amdgcn_mfma_f32_16x16x32_bf16(qah[mt], kbh[rt], acca[mt][rt], 0, 0, 0);
            acca[mt][rt] = __builtin_amdgcn_mfma_f32_16x16x32_bf16(qah[mt], kbl[rt], acca[mt][rt], 0, 0, 0);
            acca[mt][rt] = __builtin_amdgcn_mfma_f32_16x16x32_bf16(qal[mt], kbh[rt], acca[mt][rt], 0, 0, 0);
        }

    // ---- exp -> fS (overlays qS; DS ops are in-order per wave) -> coalesced store
#pragma unroll
    for (int mt = 0; mt < 4; mt++)
#pragma unroll
        for (int rt = 0; rt < 2; rt++)
#pragma unroll
            for (int reg = 0; reg < 4; reg++) {
                const int row = 16 * mt + quad * 4 + reg;
                const int col = 16 * rt + l15;
                fS[row * 32 + col] = __expf(acca[mt][rt][reg] * SCALE);
            }
#pragma unroll
    for (int i = 0; i < 8; i++) {
        const int idx = i * 64 + lane;
        const int n = idx >> 3, c4 = idx & 7;
        *(float4*)&expa[((size_t)bt * Nn + n0 + n) * 128 + w * 32 + c4 * 4] =
            *(const float4*)&fS[n * 32 + c4 * 4];
    }

    // ---- xv epilogue: +bv, through fS (after expa reads; in-order DS), -> d_out
#pragma unroll
    for (int mt = 0; mt < 4; mt++)
#pragma unroll
        for (int nt = 0; nt < 2; nt++)
#pragma unroll
            for (int reg = 0; reg < 4; reg++) {
                const int row = 16 * mt + quad * 4 + reg;
                const int col = 16 * nt + l15;
                fS[row * 32 + col] = accv[mt][nt][reg] + bvv[nt];
            }
#pragma unroll
    for (int i = 0; i < 8; i++) {
        const int idx = i * 64 + lane;
        const int n = idx >> 3, c4 = idx & 7;
        *(float4*)&out[((size_t)bt * Nn + n0 + n) * 128 + w * 32 + c4 * 4] =
            *(const float4*)&fS[n * 32 + c4 * 4];
    }
}

// ---------------------------------------------------------------------------
// k2: v1[r][d] += sum_n s1[n][r]*xv[n][d];  Z[r] += sum_n expa[n][r].
// Thread tile 4r x 4d (float4 LDS reads broadcast across the wave).
// ---------------------------------------------------------------------------
__global__ __launch_bounds__(256, 4)
void k2(const float* __restrict__ expa, const float* __restrict__ xv,
        float* __restrict__ v1, float* __restrict__ Z)
{
    __shared__ float ea[64 * 32];    // expa chunk [n][r]
    __shared__ float xvs[64 * 40];   // xv chunk [n][d] padded 40
    __shared__ float srw[64];        // 1/sum_r expa per node

    const int t  = threadIdx.x;
    const int bt = blockIdx.z;
    const int h  = blockIdx.y;
    const int nbase = blockIdx.x * 1024;

    const int dg = t & 7;          // d-group of 4
    const int rg = (t >> 3) & 7;   // r-group of 4
    const int ns = t >> 6;         // n-subset of 16 (== wave id)

    float acc[4][4];
#pragma unroll
    for (int i = 0; i < 4; i++)
#pragma unroll
        for (int j = 0; j < 4; j++) acc[i][j] = 0.f;
    float zacc[4] = {0.f, 0.f, 0.f, 0.f};

    for (int chunk = 0; chunk < 16; chunk++) {
        const int nc = nbase + chunk * 64;
#pragma unroll
        for (int i = 0; i < 2; i++) {
            const int n  = i * 32 + (t >> 3);
            const int r4 = t & 7;
            const size_t gn = (size_t)bt * Nn + nc + n;
            ((float4*)&ea[n * 32])[r4] =
                ((const float4*)(expa + gn * 128 + h * 32))[r4];
            ((float4*)&xvs[n * 40])[r4] =
                ((const float4*)(xv + gn * 128 + h * 32))[r4];
        }
        __syncthreads();
        if (t < 64) {
            float s = 0.f;
#pragma unroll
            for (int rp = 0; rp < 32; rp++) s += ea[t * 32 + ((rp + t) & 31)];
            srw[t] = 1.f / s;
        }
        __syncthreads();
#pragma unroll 4
        for (int i = 0; i < 16; i++) {
            const int n = ns * 16 + i;
            float4 e4 = *(const float4*)&ea[n * 32 + rg * 4];
            float4 xq = *(const float4*)&xvs[n * 40 + dg * 4];
            const float sw = srw[n];
            const float s0 = e4.x * sw, s1 = e4.y * sw, s2 = e4.z * sw, s3 = e4.w * sw;
            acc[0][0] += s0 * xq.x; acc[0][1] += s0 * xq.y; acc[0][2] += s0 * xq.z; acc[0][3] += s0 * xq.w;
            acc[1][0] += s1 * xq.x; acc[1][1] += s1 * xq.y; acc[1][2] += s1 * xq.z; acc[1][3] += s1 * xq.w;
            acc[2][0] += s2 * xq.x; acc[2][1] += s2 * xq.y; acc[2][2] += s2 * xq.z; acc[2][3] += s2 * xq.w;
            acc[3][0] += s3 * xq.x; acc[3][1] += s3 * xq.y; acc[3][2] += s3 * xq.z; acc[3][3] += s3 * xq.w;
            zacc[0] += e4.x; zacc[1] += e4.y; zacc[2] += e4.z; zacc[3] += e4.w;
        }
        __syncthreads();
    }

    float* v1b = v1 + (((size_t)bt * Hh + h) * Rr + rg * 4) * Dd + dg * 4;
#pragma unroll
    for (int i = 0; i < 4; i++)
#pragma unroll
        for (int j = 0; j < 4; j++)
            atomicAdd(v1b + (size_t)i * Dd + j, acc[i][j]);
    if (dg == 0) {
        float* Zb = Z + ((size_t)bt * Hh + h) * Rr + rg * 4;
#pragma unroll
        for (int i = 0; i < 4; i++) atomicAdd(Zb + i, zacc[i]);
    }
}

// ---------------------------------------------------------------------------
// k2b: v1z[bt][h][d][r] = v1[bt][h][r][d] / Z[bt][h][r]   (transpose + scale)
// ---------------------------------------------------------------------------
__global__ void k2b(const float* __restrict__ v1, const float* __restrict__ Z,
                    float* __restrict__ v1z)
{
    const int idx = blockIdx.x * 256 + threadIdx.x;   // [bt][h][d][r]
    const int r = idx & 31, d = (idx >> 5) & 31, h = (idx >> 10) & 3, bt = idx >> 12;
    const float z = Z[((size_t)bt * Hh + h) * Rr + r];
    v1z[idx] = v1[(((size_t)bt * Hh + h) * Rr + r) * Dd + d] / z;
}

// ---------------------------------------------------------------------------
// k3: v2[n,h,d] = sum_r expa[n,h,r] * v1z[h][d][r];
//     out = sigmoid(alpha_h)*xv + sigmoid(beta_h)*v2   (in place over d_out)
// ---------------------------------------------------------------------------
__global__ __launch_bounds__(256, 2)
void k3(const float* __restrict__ expa, const float* __restrict__ v1z,
        const float* __restrict__ alpha, const float* __restrict__ beta,
        float* __restrict__ out)
{
    __shared__ float eas[32 * 132];

    const int t  = threadIdx.x;
    const int bt = blockIdx.y;
    const int n0 = blockIdx.x * 32;

#pragma unroll
    for (int i = 0; i < 4; i++) {
        const int idx = i * 256 + t;
        const int n = idx >> 5, c4 = idx & 31;
        ((float4*)&eas[n * 132])[c4] =
            ((const float4*)(expa + ((size_t)bt * Nn + n0 + n) * 128))[c4];
    }

    const int j = t & 127, nh = t >> 7;
    const int h = j >> 5, d = j & 31;

    float4 vz[8];
    const float4* vp =
        (const float4*)(v1z + (((size_t)bt * Hh + h) * Dd + d) * Rr);
#pragma unroll
    for (int i = 0; i < 8; i++) vz[i] = vp[i];

    const float sa = 1.f / (1.f + __expf(-alpha[h]));
    const float sb = 1.f / (1.f + __expf(-beta[h]));

    __syncthreads();

    float* op = out + ((size_t)bt * Nn + n0) * Fc;
#pragma unroll 2
    for (int i = 0; i < 16; i++) {
        const int n = nh * 16 + i;
        const float4* er = (const float4*)&eas[n * 132 + h * 32];
        float v2 = 0.f;
#pragma unroll
        for (int r4 = 0; r4 < 8; r4++) {
            float4 e4 = er[r4];
            v2 += e4.x * vz[r4].x + e4.y * vz[r4].y +
                  e4.z * vz[r4].z + e4.w * vz[r4].w;
        }
        const size_t oi = (size_t)n * 128 + j;
        const float xvv = op[oi];
        op[oi] = sa * xvv + sb * v2;
    }
}

// ---------------------------------------------------------------------------
extern "C" void kernel_launch(void* const* d_in, const int* in_sizes, int n_in,
                              void* d_out, int out_size, void* d_ws, size_t ws_size,
                              hipStream_t stream)
{
    const float* x     = (const float*)d_in[0];
    const float* Wq    = (const float*)d_in[1];
    const float* bq    = (const float*)d_in[2];
    const float* key   = (const float*)d_in[3];
    const float* Wv    = (const float*)d_in[4];
    const float* bv    = (const float*)d_in[5];
    const float* alpha = (const float*)d_in[6];
    const float* beta  = (const float*)d_in[7];
    float* out = (float*)d_out;

    float* ws   = (float*)d_ws;
    float* expa = ws + OFF_EXPA;
    float* v1   = ws + OFF_V1;
    float* Z    = ws + OFF_Z;
    float* v1z  = ws + OFF_V1Z;
    ushort* U   = (ushort*)v1z;   // aliases v1z; k1 consumes U before k2b writes v1z

    hipMemsetAsync(v1, 0,
                   (size_t)(BT * Hh * Rr * Dd + BT * Hh * Rr) * sizeof(float),
                   stream);

    kprep<<<dim3(144), 256, 0, stream>>>(Wq, Wv, key, U);
    k1<<<dim3(Nn / 64, BT), 256, 0, stream>>>(x, bq, bv, U, expa, out);
    k2<<<dim3(4, Hh, BT), 256, 0, stream>>>(expa, out, v1, Z);
    k2b<<<dim3(BT * Hh * Rr * Dd / 256), 256, 0, stream>>>(v1, Z, v1z);
    k3<<<dim3(Nn / 32, BT), 256, 0, stream>>>(expa, v1z, alpha, beta, out);
}